// Round 11
// baseline (351.989 us; speedup 1.0000x reference)
//
#include <hip/hip_runtime.h>

static constexpr int K = 128;  // inner dim of both layers (in_ch = hid = 128)

using ushort8 = __attribute__((ext_vector_type(8))) unsigned short;
using bf16x8  = __attribute__((ext_vector_type(8))) __bf16;
using f32x4   = __attribute__((ext_vector_type(4))) float;

__device__ inline float bflo(unsigned u) { return __uint_as_float(u << 16); }
__device__ inline float bfhi(unsigned u) { return __uint_as_float(u & 0xFFFF0000u); }
__device__ inline unsigned short f2bf(float f) {  // round-to-nearest-even
    unsigned u = __float_as_uint(f);
    return (unsigned short)((u + 0x7FFF + ((u >> 16) & 1)) >> 16);
}

// ---------- CSR build via 2-level binned counting sort ----------
// bucket c = dst >> 8 (256 nodes); bucket regions ARE the final CSR regions.

__global__ __launch_bounds__(256) void k_bcount(const int* __restrict__ dst, int e,
                                                int* __restrict__ bcnt, int nb) {
    __shared__ int c[256];
    int t = threadIdx.x;
    c[t] = 0;
    __syncthreads();
    for (int i = blockIdx.x * 256 + t; i < e; i += gridDim.x * 256)
        atomicAdd(&c[dst[i] >> 8], 1);
    __syncthreads();
    if (t < nb && c[t]) atomicAdd(&bcnt[t], c[t]);
}

__global__ __launch_bounds__(256) void k_bscan(const int* __restrict__ bcnt,
                                               int* __restrict__ bbase,
                                               int* __restrict__ gcur,
                                               int nb, int* __restrict__ offs,
                                               int n, int e) {
    __shared__ int sh[256];
    int t = threadIdx.x;
    int v = (t < nb) ? bcnt[t] : 0;
    sh[t] = v;
    __syncthreads();
    for (int o = 1; o < 256; o <<= 1) {
        int x = (t >= o) ? sh[t - o] : 0;
        __syncthreads();
        sh[t] += x;
        __syncthreads();
    }
    int excl = sh[t] - v;
    bbase[t] = excl;
    gcur[t] = excl;
    if (t == 255) bbase[256] = sh[255];
    if (t == 0) offs[n] = e;
}

__global__ __launch_bounds__(256) void k_bin(const int* __restrict__ ei, int e,
                                             int* __restrict__ gcur,
                                             unsigned long long* __restrict__ tmp) {
    constexpr int PER = 4;
    __shared__ int cnt[256], base[256], cur[256];
    int t = threadIdx.x;
    int chunk0 = blockIdx.x * 256 * PER;
    cnt[t] = 0;
    __syncthreads();
    int ds[PER];
#pragma unroll
    for (int k2 = 0; k2 < PER; ++k2) {
        int i = chunk0 + k2 * 256 + t;
        ds[k2] = (i < e) ? ei[(size_t)e + i] : -1;
        if (ds[k2] >= 0) atomicAdd(&cnt[ds[k2] >> 8], 1);
    }
    __syncthreads();
    int c = cnt[t];
    base[t] = c ? atomicAdd(&gcur[t], c) : 0;
    cur[t] = 0;
    __syncthreads();
#pragma unroll
    for (int k2 = 0; k2 < PER; ++k2) {
        int i = chunk0 + k2 * 256 + t;
        if (i < e) {
            int b = ds[k2] >> 8;
            int pos = base[b] + atomicAdd(&cur[b], 1);
            tmp[pos] = ((unsigned long long)(unsigned)ds[k2] << 32) | (unsigned)ei[i];
        }
    }
}

__global__ __launch_bounds__(1024) void k_csr(const unsigned long long* __restrict__ tmp,
                                              const int* __restrict__ bbase,
                                              int* __restrict__ offs,
                                              int* __restrict__ srt,
                                              float* __restrict__ dinv, int n) {
    __shared__ int cntS[256], sh[256], cur[256];
    int b = blockIdx.x;
    int t = threadIdx.x;
    int beg = bbase[b], end = bbase[b + 1];
    if (t < 256) cntS[t] = 0;
    __syncthreads();
    for (int i = beg + t; i < end; i += 1024)
        atomicAdd(&cntS[(int)(tmp[i] >> 32) & 255], 1);
    __syncthreads();
    int v = (t < 256) ? cntS[t] : 0;
    if (t < 256) sh[t] = v;
    __syncthreads();
    for (int o = 1; o < 256; o <<= 1) {
        int x = (t < 256 && t >= o) ? sh[t - o] : 0;
        __syncthreads();
        if (t < 256) sh[t] += x;
        __syncthreads();
    }
    if (t < 256) {
        int pfx = sh[t] - v;
        int node = b * 256 + t;
        if (node < n) {
            offs[node] = beg + pfx;
            dinv[node] = rsqrtf((float)(v + 1));  // deg incl. self-loop
        }
        cur[t] = pfx;
    }
    __syncthreads();
    for (int i = beg + t; i < end; i += 1024) {
        unsigned long long pr = tmp[i];
        int d = (int)(pr >> 32);
        int pos = atomicAdd(&cur[d & 255], 1);
        srt[beg + pos] = (int)(pr & 0xFFFFFFFFu);
    }
}

// ---------- G(bf16) = dinv ⊙ (X @ W); MFMA split-bf16 (hi/lo) GEMM ----------

template <int COUT>
__global__ __launch_bounds__(256) void k_gemm_mfma(const float* __restrict__ X,
                                                   const float* __restrict__ W,
                                                   const float* __restrict__ dinv,
                                                   unsigned short* __restrict__ G, int n) {
    constexpr int BM = 64, BK = 32;
    constexpr int NCT = COUT / 16;
    constexpr int NCH = K / BK;
    constexpr int WT = COUT * (BK / 8) / 256;
    __shared__ unsigned short Ah[BM * BK], Al[BM * BK];
    __shared__ unsigned short Bh[COUT * BK], Bl[COUT * BK];
    __shared__ float dS[BM];
    const int tid = threadIdx.x;
    const int row0 = blockIdx.x * BM;
    if (tid < BM) {
        int gr = row0 + tid;
        dS[tid] = (gr < n) ? dinv[gr] : 0.f;
    }

    float4 xr[2];
    float wr[WT][8];

    auto loadX = [&](int kc) {
        int r = tid >> 2, ks = tid & 3;
        int gr = row0 + r;
        if (gr < n) {
            const float4* pp = (const float4*)(X + (size_t)gr * K + kc * BK + ks * 8);
            xr[0] = pp[0];
            xr[1] = pp[1];
        } else {
            xr[0] = make_float4(0.f, 0.f, 0.f, 0.f);
            xr[1] = xr[0];
        }
    };
    auto loadW = [&](int kc) {
#pragma unroll
        for (int q = 0; q < WT; ++q) {
            int i = tid + q * 256;
            int c = i % COUT, ks = i / COUT;
#pragma unroll
            for (int j = 0; j < 8; ++j)
                wr[q][j] = W[(size_t)(kc * BK + ks * 8 + j) * COUT + c];
        }
    };
    auto storeLDS = [&]() {
        int r = tid >> 2, ks = tid & 3;
        ushort8 h, l;
        const float* f = (const float*)&xr[0];
#pragma unroll
        for (int j = 0; j < 8; ++j) {
            unsigned short hh = f2bf(f[j]);
            h[j] = hh;
            l[j] = f2bf(f[j] - __uint_as_float((unsigned)hh << 16));
        }
        *(ushort8*)&Ah[r * BK + ks * 8] = h;
        *(ushort8*)&Al[r * BK + ks * 8] = l;
#pragma unroll
        for (int q = 0; q < WT; ++q) {
            int i = tid + q * 256;
            int c = i % COUT, ks2 = i / COUT;
            ushort8 wh, wl;
#pragma unroll
            for (int j = 0; j < 8; ++j) {
                unsigned short hh = f2bf(wr[q][j]);
                wh[j] = hh;
                wl[j] = f2bf(wr[q][j] - __uint_as_float((unsigned)hh << 16));
            }
            *(ushort8*)&Bh[c * BK + ks2 * 8] = wh;
            *(ushort8*)&Bl[c * BK + ks2 * 8] = wl;
        }
    };

    f32x4 acc[NCT] = {};
    const int l = tid & 63, wv = tid >> 6;
    const int l16 = l & 15, lk = l >> 4;
    const int arow = wv * 16 + l16;

    loadX(0);
    loadW(0);
    storeLDS();
    __syncthreads();
    for (int c = 0; c < NCH; ++c) {
        if (c + 1 < NCH) { loadX(c + 1); loadW(c + 1); }
        bf16x8 ah = *(const bf16x8*)&Ah[arow * BK + lk * 8];
        bf16x8 al = *(const bf16x8*)&Al[arow * BK + lk * 8];
#pragma unroll
        for (int ct = 0; ct < NCT; ++ct) {
            bf16x8 bh = *(const bf16x8*)&Bh[(ct * 16 + l16) * BK + lk * 8];
            bf16x8 bl = *(const bf16x8*)&Bl[(ct * 16 + l16) * BK + lk * 8];
            acc[ct] = __builtin_amdgcn_mfma_f32_16x16x32_bf16(ah, bh, acc[ct], 0, 0, 0);
            acc[ct] = __builtin_amdgcn_mfma_f32_16x16x32_bf16(al, bh, acc[ct], 0, 0, 0);
            acc[ct] = __builtin_amdgcn_mfma_f32_16x16x32_bf16(ah, bl, acc[ct], 0, 0, 0);
        }
        if (c + 1 < NCH) {
            __syncthreads();
            storeLDS();
            __syncthreads();
        }
    }

#pragma unroll
    for (int ct = 0; ct < NCT; ++ct) {
        int col = ct * 16 + l16;
#pragma unroll
        for (int r4 = 0; r4 < 4; ++r4) {
            int lr = wv * 16 + lk * 4 + r4;
            int gr = row0 + lr;
            if (gr < n) G[(size_t)gr * COUT + col] = f2bf(acc[ct][r4] * dS[lr]);
        }
    }
}

// ---------- pull-reduce: XCD-sliced columns ----------
// slice = blockIdx.x & 7 -> pins each 16-col (32 B) slice to one XCD (default
// round-robin bid%8 -> XCD). Per-XCD gather working set: 12.8 MB -> 1.6 MB.
// bf16 rows: COUT=128 -> 32 uint2/row (slice = 4 uint2); COUT=64 -> 16 uint2/row.

#define ADD4(u)                                      \
    do {                                             \
        a[0] += bflo((u).x); a[1] += bfhi((u).x);    \
        a[2] += bflo((u).y); a[3] += bfhi((u).y);    \
    } while (0)

// COUT=128: 16 edge-groups x 4 lanes; lane loads uint2 (4 cols) of its slice.
template <bool RELU>
__global__ __launch_bounds__(256) void k_reduce128(const int* __restrict__ offs,
                                                   const int* __restrict__ srt,
                                                   const uint2* __restrict__ g2,  // [n][32]
                                                   const float* __restrict__ dinv,
                                                   const float* __restrict__ bias,
                                                   float* __restrict__ out, int n) {
    const int slice = blockIdx.x & 7;
    int node = (blockIdx.x >> 3) * 4 + (threadIdx.x >> 6);
    if (node >= n) return;
    int lane = threadIdx.x & 63;
    int l4 = lane & 3, grp = lane >> 2;
    int beg = offs[node], end = offs[node + 1];
    const int cofs = slice * 4 + l4;  // uint2 idx within 32-uint2 row

    float a[4] = {};
    if (grp == 0) {  // self-loop term
        uint2 u = g2[(size_t)node * 32 + cofs];
        ADD4(u);
    }
    int j = beg + grp;
    for (; j + 16 < end; j += 32) {
        uint2 u0 = g2[(size_t)srt[j]      * 32 + cofs];
        uint2 u1 = g2[(size_t)srt[j + 16] * 32 + cofs];
        ADD4(u0); ADD4(u1);
    }
    for (; j < end; j += 16) {
        uint2 u = g2[(size_t)srt[j] * 32 + cofs];
        ADD4(u);
    }
#pragma unroll
    for (int q = 0; q < 4; ++q) {
        a[q] += __shfl_xor(a[q], 4);
        a[q] += __shfl_xor(a[q], 8);
        a[q] += __shfl_xor(a[q], 16);
        a[q] += __shfl_xor(a[q], 32);
    }
    if (lane < 4) {
        float di = dinv[node];
        float4 b = ((const float4*)bias)[slice * 4 + l4];
        float4 o;
        o.x = fmaf(di, a[0], b.x);
        o.y = fmaf(di, a[1], b.y);
        o.z = fmaf(di, a[2], b.z);
        o.w = fmaf(di, a[3], b.w);
        if (RELU) {
            o.x = fmaxf(o.x, 0.f); o.y = fmaxf(o.y, 0.f);
            o.z = fmaxf(o.z, 0.f); o.w = fmaxf(o.w, 0.f);
        }
        *(float4*)(out + (size_t)node * 128 + slice * 16 + l4 * 4) = o;
    }
}

// COUT=64: 32 edge-groups x 2 lanes; slice = 8 cols = 2 x uint2.
template <bool RELU>
__global__ __launch_bounds__(256) void k_reduce64(const int* __restrict__ offs,
                                                  const int* __restrict__ srt,
                                                  const uint2* __restrict__ g2,  // [n][16]
                                                  const float* __restrict__ dinv,
                                                  const float* __restrict__ bias,
                                                  float* __restrict__ out, int n) {
    const int slice = blockIdx.x & 7;
    int node = (blockIdx.x >> 3) * 4 + (threadIdx.x >> 6);
    if (node >= n) return;
    int lane = threadIdx.x & 63;
    int l2 = lane & 1, grp = lane >> 1;
    int beg = offs[node], end = offs[node + 1];
    const int cofs = slice * 2 + l2;  // uint2 idx within 16-uint2 row

    float a[4] = {};
    if (grp == 0) {  // self-loop term
        uint2 u = g2[(size_t)node * 16 + cofs];
        ADD4(u);
    }
    for (int j = beg + grp; j < end; j += 32) {
        uint2 u = g2[(size_t)srt[j] * 16 + cofs];
        ADD4(u);
    }
#pragma unroll
    for (int q = 0; q < 4; ++q) {
        a[q] += __shfl_xor(a[q], 2);
        a[q] += __shfl_xor(a[q], 4);
        a[q] += __shfl_xor(a[q], 8);
        a[q] += __shfl_xor(a[q], 16);
        a[q] += __shfl_xor(a[q], 32);
    }
    if (lane < 2) {
        float di = dinv[node];
        float4 b = ((const float4*)bias)[slice * 2 + l2];
        float4 o;
        o.x = fmaf(di, a[0], b.x);
        o.y = fmaf(di, a[1], b.y);
        o.z = fmaf(di, a[2], b.z);
        o.w = fmaf(di, a[3], b.w);
        if (RELU) {
            o.x = fmaxf(o.x, 0.f); o.y = fmaxf(o.y, 0.f);
            o.z = fmaxf(o.z, 0.f); o.w = fmaxf(o.w, 0.f);
        }
        *(float4*)(out + (size_t)node * 64 + slice * 8 + l2 * 4) = o;
    }
}

extern "C" void kernel_launch(void* const* d_in, const int* in_sizes, int n_in,
                              void* d_out, int out_size, void* d_ws, size_t ws_size,
                              hipStream_t stream) {
    const float* x  = (const float*)d_in[0];
    const int*   ei = (const int*)d_in[1];   // [2, E] int32
    const float* W1 = (const float*)d_in[2];
    const float* b1 = (const float*)d_in[3];
    const float* W2 = (const float*)d_in[4];
    const float* b2 = (const float*)d_in[5];
    float* out = (float*)d_out;

    const int n = in_sizes[0] / K;   // 50000
    const int e = in_sizes[1] / 2;   // 800000
    const int nb = (n + 255) / 256;  // 196 buckets

    // workspace layout (8B-aligned head first)
    char* p = (char*)d_ws;
    unsigned long long* tmp = (unsigned long long*)p;  p += (size_t)e * 8;  // (dst,src) pairs
    int* bcnt  = (int*)p;  p += 256 * 4;
    int* bbase = (int*)p;  p += 257 * 4;
    int* gcur  = (int*)p;  p += 256 * 4;
    int* offs  = (int*)p;  p += (size_t)(n + 1) * 4;
    int* srt   = (int*)p;  p += (size_t)e * 4;
    float* dinv = (float*)p;  p += (size_t)n * 4;
    p = (char*)(((uintptr_t)p + 15) & ~(uintptr_t)15);
    unsigned short* G1 = (unsigned short*)p;  p += (size_t)n * 128 * 2;  // bf16 [n][128]
    p = (char*)(((uintptr_t)p + 15) & ~(uintptr_t)15);
    float* H = (float*)p;  p += (size_t)n * 128 * 4;                     // fp32 [n][128]
    p = (char*)(((uintptr_t)p + 15) & ~(uintptr_t)15);
    unsigned short* G2 = (unsigned short*)p;                             // bf16 [n][64]

    // CSR build
    hipMemsetAsync(bcnt, 0, 256 * sizeof(int), stream);
    k_bcount<<<512, 256, 0, stream>>>(ei + e, e, bcnt, nb);
    k_bscan<<<1, 256, 0, stream>>>(bcnt, bbase, gcur, nb, offs, n, e);
    k_bin<<<(e + 1023) / 1024, 256, 0, stream>>>(ei, e, gcur, tmp);
    k_csr<<<nb, 1024, 0, stream>>>(tmp, bbase, offs, srt, dinv, n);

    // Layer 1: H = relu(dinv ⊙ (A_hat G1) + b1), G1 = dinv ⊙ (x@W1)
    k_gemm_mfma<128><<<(n + 63) / 64, 256, 0, stream>>>(x, W1, dinv, G1, n);
    k_reduce128<true><<<((n + 3) / 4) * 8, 256, 0, stream>>>(offs, srt, (const uint2*)G1,
                                                             dinv, b1, H, n);

    // Layer 2: out = dinv ⊙ (A_hat G2) + b2, G2 = dinv ⊙ (H@W2)
    k_gemm_mfma<64><<<(n + 63) / 64, 256, 0, stream>>>(H, W2, dinv, G2, n);
    k_reduce64<false><<<((n + 3) / 4) * 8, 256, 0, stream>>>(offs, srt, (const uint2*)G2,
                                                             dinv, b2, out, n);
}

// Round 12
// 135.026 us; speedup vs baseline: 2.6068x; 2.6068x over previous
//
#include <hip/hip_runtime.h>

static constexpr int K = 128;    // inner dim of both layers
static constexpr int CAP = 8192; // bucket capacity (mean 4096, Poisson sd 64)

using ushort8 = __attribute__((ext_vector_type(8))) unsigned short;
using bf16x8  = __attribute__((ext_vector_type(8))) __bf16;
using f32x4   = __attribute__((ext_vector_type(4))) float;

__device__ inline float bflo(unsigned u) { return __uint_as_float(u << 16); }
__device__ inline float bfhi(unsigned u) { return __uint_as_float(u & 0xFFFF0000u); }
__device__ inline unsigned short f2bf(float f) {  // round-to-nearest-even
    unsigned u = __float_as_uint(f);
    return (unsigned short)((u + 0x7FFF + ((u >> 16) & 1)) >> 16);
}

// ---------- CSR build: fixed-capacity binned sort (no pre-count pass) ----------
// bucket b = dst >> 8; tmp region [b*CAP, b*CAP+cnt). Bucket regions compact to
// the final CSR layout via bbase scan.

__global__ __launch_bounds__(256) void k_bin(const int* __restrict__ ei, int e,
                                             int* __restrict__ gcur,
                                             unsigned long long* __restrict__ tmp) {
    constexpr int PER = 4;
    __shared__ int cnt[256], base[256], cur[256];
    int t = threadIdx.x;
    int chunk0 = blockIdx.x * 256 * PER;
    cnt[t] = 0;
    __syncthreads();
    int ds[PER];
#pragma unroll
    for (int k2 = 0; k2 < PER; ++k2) {
        int i = chunk0 + k2 * 256 + t;
        ds[k2] = (i < e) ? ei[(size_t)e + i] : -1;
        if (ds[k2] >= 0) atomicAdd(&cnt[ds[k2] >> 8], 1);
    }
    __syncthreads();
    int c = cnt[t];
    base[t] = c ? atomicAdd(&gcur[t], c) : 0;
    cur[t] = 0;
    __syncthreads();
#pragma unroll
    for (int k2 = 0; k2 < PER; ++k2) {
        int i = chunk0 + k2 * 256 + t;
        if (i < e) {
            int b = ds[k2] >> 8;
            int pos = base[b] + atomicAdd(&cur[b], 1);
            tmp[(size_t)b * CAP + pos] =
                ((unsigned long long)(unsigned)ds[k2] << 32) | (unsigned)ei[i];
        }
    }
}

// 1 block: scan bucket counts (gcur) -> bbase; offs[n] = e
__global__ __launch_bounds__(256) void k_bscan(const int* __restrict__ gcur,
                                               int* __restrict__ bbase,
                                               int nb, int* __restrict__ offs,
                                               int n, int e) {
    __shared__ int sh[256];
    int t = threadIdx.x;
    int v = (t < nb) ? gcur[t] : 0;
    sh[t] = v;
    __syncthreads();
    for (int o = 1; o < 256; o <<= 1) {
        int x = (t >= o) ? sh[t - o] : 0;
        __syncthreads();
        sh[t] += x;
        __syncthreads();
    }
    bbase[t] = sh[t] - v;
    if (t == 255) bbase[256] = sh[255];
    if (t == 0) offs[n] = e;
}

__global__ __launch_bounds__(1024) void k_csr(const unsigned long long* __restrict__ tmp,
                                              const int* __restrict__ bbase,
                                              int* __restrict__ offs,
                                              int* __restrict__ srt,
                                              float* __restrict__ dinv, int n) {
    __shared__ int cntS[256], sh[256], cur[256];
    int b = blockIdx.x;
    int t = threadIdx.x;
    int beg = bbase[b];
    int tot = bbase[b + 1] - beg;
    const unsigned long long* tb = tmp + (size_t)b * CAP;
    if (t < 256) cntS[t] = 0;
    __syncthreads();
    for (int i = t; i < tot; i += 1024)
        atomicAdd(&cntS[(int)(tb[i] >> 32) & 255], 1);
    __syncthreads();
    int v = (t < 256) ? cntS[t] : 0;
    if (t < 256) sh[t] = v;
    __syncthreads();
    for (int o = 1; o < 256; o <<= 1) {
        int x = (t < 256 && t >= o) ? sh[t - o] : 0;
        __syncthreads();
        if (t < 256) sh[t] += x;
        __syncthreads();
    }
    if (t < 256) {
        int pfx = sh[t] - v;
        int node = b * 256 + t;
        if (node < n) {
            offs[node] = beg + pfx;
            dinv[node] = rsqrtf((float)(v + 1));  // deg incl. self-loop
        }
        cur[t] = pfx;
    }
    __syncthreads();
    for (int i = t; i < tot; i += 1024) {
        unsigned long long pr = tb[i];
        int d = (int)(pr >> 32);
        int pos = atomicAdd(&cur[d & 255], 1);
        srt[beg + pos] = (int)(pr & 0xFFFFFFFFu);
    }
}

// ---------- G(bf16) = dinv ⊙ (X @ W); MFMA split-bf16 (hi/lo), fp32 X ----------

template <int COUT>
__global__ __launch_bounds__(256) void k_gemm_mfma(const float* __restrict__ X,
                                                   const float* __restrict__ W,
                                                   const float* __restrict__ dinv,
                                                   unsigned short* __restrict__ G, int n) {
    constexpr int BM = 64, BK = 32;
    constexpr int NCT = COUT / 16;
    constexpr int NCH = K / BK;
    constexpr int WT = COUT * (BK / 8) / 256;
    __shared__ unsigned short Ah[BM * BK], Al[BM * BK];
    __shared__ unsigned short Bh[COUT * BK], Bl[COUT * BK];
    __shared__ float dS[BM];
    const int tid = threadIdx.x;
    const int row0 = blockIdx.x * BM;
    if (tid < BM) {
        int gr = row0 + tid;
        dS[tid] = (gr < n) ? dinv[gr] : 0.f;
    }

    float4 xr[2];
    float wr[WT][8];

    auto loadX = [&](int kc) {
        int r = tid >> 2, ks = tid & 3;
        int gr = row0 + r;
        if (gr < n) {
            const float4* pp = (const float4*)(X + (size_t)gr * K + kc * BK + ks * 8);
            xr[0] = pp[0];
            xr[1] = pp[1];
        } else {
            xr[0] = make_float4(0.f, 0.f, 0.f, 0.f);
            xr[1] = xr[0];
        }
    };
    auto loadW = [&](int kc) {
#pragma unroll
        for (int q = 0; q < WT; ++q) {
            int i = tid + q * 256;
            int c = i % COUT, ks = i / COUT;
#pragma unroll
            for (int j = 0; j < 8; ++j)
                wr[q][j] = W[(size_t)(kc * BK + ks * 8 + j) * COUT + c];
        }
    };
    auto storeLDS = [&]() {
        int r = tid >> 2, ks = tid & 3;
        ushort8 h, l;
        const float* f = (const float*)&xr[0];
#pragma unroll
        for (int j = 0; j < 8; ++j) {
            unsigned short hh = f2bf(f[j]);
            h[j] = hh;
            l[j] = f2bf(f[j] - __uint_as_float((unsigned)hh << 16));
        }
        *(ushort8*)&Ah[r * BK + ks * 8] = h;
        *(ushort8*)&Al[r * BK + ks * 8] = l;
#pragma unroll
        for (int q = 0; q < WT; ++q) {
            int i = tid + q * 256;
            int c = i % COUT, ks2 = i / COUT;
            ushort8 wh, wl;
#pragma unroll
            for (int j = 0; j < 8; ++j) {
                unsigned short hh = f2bf(wr[q][j]);
                wh[j] = hh;
                wl[j] = f2bf(wr[q][j] - __uint_as_float((unsigned)hh << 16));
            }
            *(ushort8*)&Bh[c * BK + ks2 * 8] = wh;
            *(ushort8*)&Bl[c * BK + ks2 * 8] = wl;
        }
    };

    f32x4 acc[NCT] = {};
    const int l = tid & 63, wv = tid >> 6;
    const int l16 = l & 15, lk = l >> 4;
    const int arow = wv * 16 + l16;

    loadX(0);
    loadW(0);
    storeLDS();
    __syncthreads();
    for (int c = 0; c < NCH; ++c) {
        if (c + 1 < NCH) { loadX(c + 1); loadW(c + 1); }
        bf16x8 ah = *(const bf16x8*)&Ah[arow * BK + lk * 8];
        bf16x8 al = *(const bf16x8*)&Al[arow * BK + lk * 8];
#pragma unroll
        for (int ct = 0; ct < NCT; ++ct) {
            bf16x8 bh = *(const bf16x8*)&Bh[(ct * 16 + l16) * BK + lk * 8];
            bf16x8 bl = *(const bf16x8*)&Bl[(ct * 16 + l16) * BK + lk * 8];
            acc[ct] = __builtin_amdgcn_mfma_f32_16x16x32_bf16(ah, bh, acc[ct], 0, 0, 0);
            acc[ct] = __builtin_amdgcn_mfma_f32_16x16x32_bf16(al, bh, acc[ct], 0, 0, 0);
            acc[ct] = __builtin_amdgcn_mfma_f32_16x16x32_bf16(ah, bl, acc[ct], 0, 0, 0);
        }
        if (c + 1 < NCH) {
            __syncthreads();
            storeLDS();
            __syncthreads();
        }
    }

#pragma unroll
    for (int ct = 0; ct < NCT; ++ct) {
        int col = ct * 16 + l16;
#pragma unroll
        for (int r4 = 0; r4 < 4; ++r4) {
            int lr = wv * 16 + lk * 4 + r4;
            int gr = row0 + lr;
            if (gr < n) G[(size_t)gr * COUT + col] = f2bf(acc[ct][r4] * dS[lr]);
        }
    }
}

// ---------- G2(bf16) = dinv ⊙ (H @ W2); H already bf16 -> A-side exact, 2 MFMAs ----------

__global__ __launch_bounds__(256) void k_gemm_bf16(const unsigned short* __restrict__ X,
                                                   const float* __restrict__ W,
                                                   const float* __restrict__ dinv,
                                                   unsigned short* __restrict__ G, int n) {
    constexpr int COUT = 64, BM = 64, BK = 32;
    constexpr int NCT = COUT / 16;  // 4
    constexpr int NCH = K / BK;     // 4
    __shared__ unsigned short Ah[BM * BK];
    __shared__ unsigned short Bh[COUT * BK], Bl[COUT * BK];
    __shared__ float dS[BM];
    const int tid = threadIdx.x;
    const int row0 = blockIdx.x * BM;
    if (tid < BM) {
        int gr = row0 + tid;
        dS[tid] = (gr < n) ? dinv[gr] : 0.f;
    }

    ushort8 xrb;
    float wr[8];

    auto loadX = [&](int kc) {
        int r = tid >> 2, ks = tid & 3;
        int gr = row0 + r;
        if (gr < n)
            xrb = *(const ushort8*)(X + (size_t)gr * K + kc * BK + ks * 8);
        else
            xrb = (ushort8){0, 0, 0, 0, 0, 0, 0, 0};
    };
    auto loadW = [&](int kc) {
        int c = tid % COUT, ks = tid / COUT;
#pragma unroll
        for (int j = 0; j < 8; ++j)
            wr[j] = W[(size_t)(kc * BK + ks * 8 + j) * COUT + c];
    };
    auto storeLDS = [&]() {
        int r = tid >> 2, ks = tid & 3;
        *(ushort8*)&Ah[r * BK + ks * 8] = xrb;
        int c = tid % COUT, ks2 = tid / COUT;
        ushort8 wh, wl;
#pragma unroll
        for (int j = 0; j < 8; ++j) {
            unsigned short hh = f2bf(wr[j]);
            wh[j] = hh;
            wl[j] = f2bf(wr[j] - __uint_as_float((unsigned)hh << 16));
        }
        *(ushort8*)&Bh[c * BK + ks2 * 8] = wh;
        *(ushort8*)&Bl[c * BK + ks2 * 8] = wl;
    };

    f32x4 acc[NCT] = {};
    const int l = tid & 63, wv = tid >> 6;
    const int l16 = l & 15, lk = l >> 4;
    const int arow = wv * 16 + l16;

    loadX(0);
    loadW(0);
    storeLDS();
    __syncthreads();
    for (int c = 0; c < NCH; ++c) {
        if (c + 1 < NCH) { loadX(c + 1); loadW(c + 1); }
        bf16x8 ah = *(const bf16x8*)&Ah[arow * BK + lk * 8];
#pragma unroll
        for (int ct = 0; ct < NCT; ++ct) {
            bf16x8 bh = *(const bf16x8*)&Bh[(ct * 16 + l16) * BK + lk * 8];
            bf16x8 bl = *(const bf16x8*)&Bl[(ct * 16 + l16) * BK + lk * 8];
            acc[ct] = __builtin_amdgcn_mfma_f32_16x16x32_bf16(ah, bh, acc[ct], 0, 0, 0);
            acc[ct] = __builtin_amdgcn_mfma_f32_16x16x32_bf16(ah, bl, acc[ct], 0, 0, 0);
        }
        if (c + 1 < NCH) {
            __syncthreads();
            storeLDS();
            __syncthreads();
        }
    }

#pragma unroll
    for (int ct = 0; ct < NCT; ++ct) {
        int col = ct * 16 + l16;
#pragma unroll
        for (int r4 = 0; r4 < 4; ++r4) {
            int lr = wv * 16 + lk * 4 + r4;
            int gr = row0 + lr;
            if (gr < n) G[(size_t)gr * COUT + col] = f2bf(acc[ct][r4] * dS[lr]);
        }
    }
}

// ---------- pull-reduce (round-8 structure: sub-wave groups, uint4 gathers) ----------

#define ADD8(u)                                      \
    do {                                             \
        a[0] += bflo((u).x); a[1] += bfhi((u).x);    \
        a[2] += bflo((u).y); a[3] += bfhi((u).y);    \
        a[4] += bflo((u).z); a[5] += bfhi((u).z);    \
        a[6] += bflo((u).w); a[7] += bfhi((u).w);    \
    } while (0)

// Layer 1: 4 groups x 16 lanes; gathers uint4/lane from G1; writes bf16 H + relu.
__global__ __launch_bounds__(256) void k_reduce128(const int* __restrict__ offs,
                                                   const int* __restrict__ srt,
                                                   const uint4* __restrict__ g4,  // [n][16]
                                                   const float* __restrict__ dinv,
                                                   const float* __restrict__ bias,
                                                   unsigned short* __restrict__ out, int n) {
    int node = blockIdx.x * 4 + (threadIdx.x >> 6);
    if (node >= n) return;
    int lane = threadIdx.x & 63;
    int l16 = lane & 15, grp = lane >> 4;
    int beg = offs[node], end = offs[node + 1];

    float a[8] = {};
    if (grp == 0) {  // self-loop term
        uint4 u = g4[(size_t)node * 16 + l16];
        ADD8(u);
    }
    int j = beg + grp;
    for (; j + 12 < end; j += 16) {
        uint4 u0 = g4[(size_t)srt[j]      * 16 + l16];
        uint4 u1 = g4[(size_t)srt[j + 4]  * 16 + l16];
        uint4 u2 = g4[(size_t)srt[j + 8]  * 16 + l16];
        uint4 u3 = g4[(size_t)srt[j + 12] * 16 + l16];
        ADD8(u0); ADD8(u1); ADD8(u2); ADD8(u3);
    }
    for (; j < end; j += 4) {
        uint4 u = g4[(size_t)srt[j] * 16 + l16];
        ADD8(u);
    }
#pragma unroll
    for (int q = 0; q < 8; ++q) {
        a[q] += __shfl_xor(a[q], 16);
        a[q] += __shfl_xor(a[q], 32);
    }
    if (lane < 16) {
        float di = dinv[node];
        ushort8 o;
#pragma unroll
        for (int q = 0; q < 8; ++q) {
            float v = fmaf(di, a[q], bias[l16 * 8 + q]);
            o[q] = f2bf(fmaxf(v, 0.f));  // relu
        }
        *(ushort8*)(out + (size_t)node * 128 + l16 * 8) = o;
    }
}

// Layer 2: 8 groups x 8 lanes; gathers uint4/lane from G2; writes fp32 out (no relu).
__global__ __launch_bounds__(256) void k_reduce64(const int* __restrict__ offs,
                                                  const int* __restrict__ srt,
                                                  const uint4* __restrict__ g4,  // [n][8]
                                                  const float* __restrict__ dinv,
                                                  const float* __restrict__ bias,
                                                  float* __restrict__ out, int n) {
    int node = blockIdx.x * 4 + (threadIdx.x >> 6);
    if (node >= n) return;
    int lane = threadIdx.x & 63;
    int l8 = lane & 7, grp = lane >> 3;
    int beg = offs[node], end = offs[node + 1];

    float a[8] = {};
    if (grp == 0) {  // self-loop term
        uint4 u = g4[(size_t)node * 8 + l8];
        ADD8(u);
    }
    int j = beg + grp;
    for (; j + 8 < end; j += 16) {
        uint4 u0 = g4[(size_t)srt[j]     * 8 + l8];
        uint4 u1 = g4[(size_t)srt[j + 8] * 8 + l8];
        ADD8(u0); ADD8(u1);
    }
    for (; j < end; j += 8) {
        uint4 u = g4[(size_t)srt[j] * 8 + l8];
        ADD8(u);
    }
#pragma unroll
    for (int q = 0; q < 8; ++q) {
        a[q] += __shfl_xor(a[q], 8);
        a[q] += __shfl_xor(a[q], 16);
        a[q] += __shfl_xor(a[q], 32);
    }
    if (lane < 8) {
        float di = dinv[node];
        float4 b0 = ((const float4*)bias)[l8 * 2];
        float4 b1 = ((const float4*)bias)[l8 * 2 + 1];
        float4 o0, o1;
        o0.x = fmaf(di, a[0], b0.x); o0.y = fmaf(di, a[1], b0.y);
        o0.z = fmaf(di, a[2], b0.z); o0.w = fmaf(di, a[3], b0.w);
        o1.x = fmaf(di, a[4], b1.x); o1.y = fmaf(di, a[5], b1.y);
        o1.z = fmaf(di, a[6], b1.z); o1.w = fmaf(di, a[7], b1.w);
        float4* op = (float4*)(out + (size_t)node * 64 + l8 * 8);
        op[0] = o0;
        op[1] = o1;
    }
}

extern "C" void kernel_launch(void* const* d_in, const int* in_sizes, int n_in,
                              void* d_out, int out_size, void* d_ws, size_t ws_size,
                              hipStream_t stream) {
    const float* x  = (const float*)d_in[0];
    const int*   ei = (const int*)d_in[1];   // [2, E] int32
    const float* W1 = (const float*)d_in[2];
    const float* b1 = (const float*)d_in[3];
    const float* W2 = (const float*)d_in[4];
    const float* b2 = (const float*)d_in[5];
    float* out = (float*)d_out;

    const int n = in_sizes[0] / K;   // 50000
    const int e = in_sizes[1] / 2;   // 800000
    const int nb = (n + 255) / 256;  // 196 buckets

    // workspace layout (8B-aligned head first)
    char* p = (char*)d_ws;
    unsigned long long* tmp = (unsigned long long*)p;  p += (size_t)nb * CAP * 8;  // binned pairs
    int* gcur  = (int*)p;  p += 256 * 4;
    int* bbase = (int*)p;  p += 257 * 4;
    int* offs  = (int*)p;  p += (size_t)(n + 1) * 4;
    int* srt   = (int*)p;  p += (size_t)e * 4;
    float* dinv = (float*)p;  p += (size_t)n * 4;
    p = (char*)(((uintptr_t)p + 15) & ~(uintptr_t)15);
    unsigned short* G1 = (unsigned short*)p;  p += (size_t)n * 128 * 2;  // bf16 [n][128]
    p = (char*)(((uintptr_t)p + 15) & ~(uintptr_t)15);
    unsigned short* H = (unsigned short*)p;   p += (size_t)n * 128 * 2;  // bf16 [n][128]
    p = (char*)(((uintptr_t)p + 15) & ~(uintptr_t)15);
    unsigned short* G2 = (unsigned short*)p;                             // bf16 [n][64]

    // CSR build (no pre-count pass)
    hipMemsetAsync(gcur, 0, 256 * sizeof(int), stream);
    k_bin<<<(e + 1023) / 1024, 256, 0, stream>>>(ei, e, gcur, tmp);
    k_bscan<<<1, 256, 0, stream>>>(gcur, bbase, nb, offs, n, e);
    k_csr<<<nb, 1024, 0, stream>>>(tmp, bbase, offs, srt, dinv, n);

    // Layer 1: H(bf16) = relu(dinv ⊙ (A_hat G1) + b1), G1 = dinv ⊙ (x@W1)
    k_gemm_mfma<128><<<(n + 63) / 64, 256, 0, stream>>>(x, W1, dinv, G1, n);
    k_reduce128<<<(n + 3) / 4, 256, 0, stream>>>(offs, srt, (const uint4*)G1,
                                                 dinv, b1, H, n);

    // Layer 2: out = dinv ⊙ (A_hat G2) + b2, G2 = dinv ⊙ (H@W2)
    k_gemm_bf16<<<(n + 63) / 64, 256, 0, stream>>>(H, W2, dinv, G2, n);
    k_reduce64<<<(n + 3) / 4, 256, 0, stream>>>(offs, srt, (const uint4*)G2,
                                                dinv, b2, out, n);
}

// Round 13
// 129.875 us; speedup vs baseline: 2.7102x; 1.0397x over previous
//
#include <hip/hip_runtime.h>

static constexpr int K = 128;    // inner dim of both layers
static constexpr int CAP = 8192; // bucket capacity (mean 4096, Poisson sd 64)

using ushort8 = __attribute__((ext_vector_type(8))) unsigned short;
using bf16x8  = __attribute__((ext_vector_type(8))) __bf16;
using f32x4   = __attribute__((ext_vector_type(4))) float;

__device__ inline float bflo(unsigned u) { return __uint_as_float(u << 16); }
__device__ inline float bfhi(unsigned u) { return __uint_as_float(u & 0xFFFF0000u); }
__device__ inline unsigned short f2bf(float f) {  // round-to-nearest-even
    unsigned u = __float_as_uint(f);
    return (unsigned short)((u + 0x7FFF + ((u >> 16) & 1)) >> 16);
}

// ---------- CSR build: fixed-capacity binned sort (no pre-count, no scan kernel) ----------
// bucket b = dst >> 8; tmp region [b*CAP, b*CAP+cnt). gcur[b] = bucket count.

__global__ __launch_bounds__(256) void k_bin(const int* __restrict__ ei, int e,
                                             int* __restrict__ gcur,
                                             unsigned long long* __restrict__ tmp) {
    constexpr int PER = 4;
    __shared__ int cnt[256], base[256], cur[256];
    int t = threadIdx.x;
    int chunk0 = blockIdx.x * 256 * PER;
    cnt[t] = 0;
    __syncthreads();
    int ds[PER];
#pragma unroll
    for (int k2 = 0; k2 < PER; ++k2) {
        int i = chunk0 + k2 * 256 + t;
        ds[k2] = (i < e) ? ei[(size_t)e + i] : -1;
        if (ds[k2] >= 0) atomicAdd(&cnt[ds[k2] >> 8], 1);
    }
    __syncthreads();
    int c = cnt[t];
    base[t] = c ? atomicAdd(&gcur[t], c) : 0;
    cur[t] = 0;
    __syncthreads();
#pragma unroll
    for (int k2 = 0; k2 < PER; ++k2) {
        int i = chunk0 + k2 * 256 + t;
        if (i < e) {
            int b = ds[k2] >> 8;
            int pos = base[b] + atomicAdd(&cur[b], 1);
            tmp[(size_t)b * CAP + pos] =
                ((unsigned long long)(unsigned)ds[k2] << 32) | (unsigned)ei[i];
        }
    }
}

// one block per bucket: self-computed prefix (beg), register-cached pairs,
// per-node counts -> offs/dinv, place src into srt window.
__global__ __launch_bounds__(1024) void k_csr(const unsigned long long* __restrict__ tmp,
                                              const int* __restrict__ gcur,
                                              int* __restrict__ offs,
                                              int* __restrict__ srt,
                                              float* __restrict__ dinv, int n, int e) {
    __shared__ int cntS[256], sh[256], cur[256], bsum[256];
    const int b = blockIdx.x;
    const int t = threadIdx.x;
    const int tot = gcur[b];
    const unsigned long long* tb = tmp + (size_t)b * CAP;

    // cache this block's pairs in registers (CAP/1024 = 8 max per thread)
    unsigned long long pr[8];
#pragma unroll
    for (int p = 0; p < 8; ++p) {
        int i = t + p * 1024;
        pr[p] = (i < tot) ? tb[i] : 0;
    }

    // global prefix: beg = sum gcur[0..b-1]
    if (t < 256) bsum[t] = (t < b) ? gcur[t] : 0;
    if (t < 256) cntS[t] = 0;
    __syncthreads();
    for (int o = 128; o > 0; o >>= 1) {
        if (t < o) bsum[t] += bsum[t + o];
        __syncthreads();
    }
    const int beg = bsum[0];

    // per-node counts
#pragma unroll
    for (int p = 0; p < 8; ++p) {
        int i = t + p * 1024;
        if (i < tot) atomicAdd(&cntS[(int)(pr[p] >> 32) & 255], 1);
    }
    __syncthreads();
    int v = (t < 256) ? cntS[t] : 0;
    if (t < 256) sh[t] = v;
    __syncthreads();
    for (int o = 1; o < 256; o <<= 1) {
        int x = (t < 256 && t >= o) ? sh[t - o] : 0;
        __syncthreads();
        if (t < 256) sh[t] += x;
        __syncthreads();
    }
    if (t < 256) {
        int pfx = sh[t] - v;
        int node = b * 256 + t;
        if (node < n) {
            offs[node] = beg + pfx;
            dinv[node] = rsqrtf((float)(v + 1));  // deg incl. self-loop
        }
        cur[t] = pfx;
    }
    if (b == (int)gridDim.x - 1 && t == 0) offs[n] = e;
    __syncthreads();
#pragma unroll
    for (int p = 0; p < 8; ++p) {
        int i = t + p * 1024;
        if (i < tot) {
            int d = (int)(pr[p] >> 32);
            int pos = atomicAdd(&cur[d & 255], 1);
            srt[beg + pos] = (int)(pr[p] & 0xFFFFFFFFu);
        }
    }
}

// ---------- G1(bf16) = dinv ⊙ (X @ W1); X split hi/lo, W hi-only (2 MFMAs) ----------

template <int COUT>
__global__ __launch_bounds__(256) void k_gemm_mfma(const float* __restrict__ X,
                                                   const float* __restrict__ W,
                                                   const float* __restrict__ dinv,
                                                   unsigned short* __restrict__ G, int n) {
    constexpr int BM = 64, BK = 32;
    constexpr int NCT = COUT / 16;
    constexpr int NCH = K / BK;
    constexpr int WT = COUT * (BK / 8) / 256;
    __shared__ unsigned short Ah[BM * BK], Al[BM * BK];
    __shared__ unsigned short Bh[COUT * BK];
    __shared__ float dS[BM];
    const int tid = threadIdx.x;
    const int row0 = blockIdx.x * BM;
    if (tid < BM) {
        int gr = row0 + tid;
        dS[tid] = (gr < n) ? dinv[gr] : 0.f;
    }

    float4 xr[2];
    float wr[WT][8];

    auto loadX = [&](int kc) {
        int r = tid >> 2, ks = tid & 3;
        int gr = row0 + r;
        if (gr < n) {
            const float4* pp = (const float4*)(X + (size_t)gr * K + kc * BK + ks * 8);
            xr[0] = pp[0];
            xr[1] = pp[1];
        } else {
            xr[0] = make_float4(0.f, 0.f, 0.f, 0.f);
            xr[1] = xr[0];
        }
    };
    auto loadW = [&](int kc) {
#pragma unroll
        for (int q = 0; q < WT; ++q) {
            int i = tid + q * 256;
            int c = i % COUT, ks = i / COUT;
#pragma unroll
            for (int j = 0; j < 8; ++j)
                wr[q][j] = W[(size_t)(kc * BK + ks * 8 + j) * COUT + c];
        }
    };
    auto storeLDS = [&]() {
        int r = tid >> 2, ks = tid & 3;
        ushort8 h, l;
        const float* f = (const float*)&xr[0];
#pragma unroll
        for (int j = 0; j < 8; ++j) {
            unsigned short hh = f2bf(f[j]);
            h[j] = hh;
            l[j] = f2bf(f[j] - __uint_as_float((unsigned)hh << 16));
        }
        *(ushort8*)&Ah[r * BK + ks * 8] = h;
        *(ushort8*)&Al[r * BK + ks * 8] = l;
#pragma unroll
        for (int q = 0; q < WT; ++q) {
            int i = tid + q * 256;
            int c = i % COUT, ks2 = i / COUT;
            ushort8 wh;
#pragma unroll
            for (int j = 0; j < 8; ++j) wh[j] = f2bf(wr[q][j]);
            *(ushort8*)&Bh[c * BK + ks2 * 8] = wh;
        }
    };

    f32x4 acc[NCT] = {};
    const int l = tid & 63, wv = tid >> 6;
    const int l16 = l & 15, lk = l >> 4;
    const int arow = wv * 16 + l16;

    loadX(0);
    loadW(0);
    storeLDS();
    __syncthreads();
    for (int c = 0; c < NCH; ++c) {
        if (c + 1 < NCH) { loadX(c + 1); loadW(c + 1); }
        bf16x8 ah = *(const bf16x8*)&Ah[arow * BK + lk * 8];
        bf16x8 al = *(const bf16x8*)&Al[arow * BK + lk * 8];
#pragma unroll
        for (int ct = 0; ct < NCT; ++ct) {
            bf16x8 bh = *(const bf16x8*)&Bh[(ct * 16 + l16) * BK + lk * 8];
            acc[ct] = __builtin_amdgcn_mfma_f32_16x16x32_bf16(ah, bh, acc[ct], 0, 0, 0);
            acc[ct] = __builtin_amdgcn_mfma_f32_16x16x32_bf16(al, bh, acc[ct], 0, 0, 0);
        }
        if (c + 1 < NCH) {
            __syncthreads();
            storeLDS();
            __syncthreads();
        }
    }

#pragma unroll
    for (int ct = 0; ct < NCT; ++ct) {
        int col = ct * 16 + l16;
#pragma unroll
        for (int r4 = 0; r4 < 4; ++r4) {
            int lr = wv * 16 + lk * 4 + r4;
            int gr = row0 + lr;
            if (gr < n) G[(size_t)gr * COUT + col] = f2bf(acc[ct][r4] * dS[lr]);
        }
    }
}

// ---------- G2(bf16) = dinv ⊙ (H @ W2); H bf16 exact, W hi-only (1 MFMA) ----------

__global__ __launch_bounds__(256) void k_gemm_bf16(const unsigned short* __restrict__ X,
                                                   const float* __restrict__ W,
                                                   const float* __restrict__ dinv,
                                                   unsigned short* __restrict__ G, int n) {
    constexpr int COUT = 64, BM = 64, BK = 32;
    constexpr int NCT = COUT / 16;  // 4
    constexpr int NCH = K / BK;     // 4
    __shared__ unsigned short Ah[BM * BK];
    __shared__ unsigned short Bh[COUT * BK];
    __shared__ float dS[BM];
    const int tid = threadIdx.x;
    const int row0 = blockIdx.x * BM;
    if (tid < BM) {
        int gr = row0 + tid;
        dS[tid] = (gr < n) ? dinv[gr] : 0.f;
    }

    ushort8 xrb;
    float wr[8];

    auto loadX = [&](int kc) {
        int r = tid >> 2, ks = tid & 3;
        int gr = row0 + r;
        if (gr < n)
            xrb = *(const ushort8*)(X + (size_t)gr * K + kc * BK + ks * 8);
        else
            xrb = (ushort8){0, 0, 0, 0, 0, 0, 0, 0};
    };
    auto loadW = [&](int kc) {
        int c = tid % COUT, ks = tid / COUT;
#pragma unroll
        for (int j = 0; j < 8; ++j)
            wr[j] = W[(size_t)(kc * BK + ks * 8 + j) * COUT + c];
    };
    auto storeLDS = [&]() {
        int r = tid >> 2, ks = tid & 3;
        *(ushort8*)&Ah[r * BK + ks * 8] = xrb;
        int c = tid % COUT, ks2 = tid / COUT;
        ushort8 wh;
#pragma unroll
        for (int j = 0; j < 8; ++j) wh[j] = f2bf(wr[j]);
        *(ushort8*)&Bh[c * BK + ks2 * 8] = wh;
    };

    f32x4 acc[NCT] = {};
    const int l = tid & 63, wv = tid >> 6;
    const int l16 = l & 15, lk = l >> 4;
    const int arow = wv * 16 + l16;

    loadX(0);
    loadW(0);
    storeLDS();
    __syncthreads();
    for (int c = 0; c < NCH; ++c) {
        if (c + 1 < NCH) { loadX(c + 1); loadW(c + 1); }
        bf16x8 ah = *(const bf16x8*)&Ah[arow * BK + lk * 8];
#pragma unroll
        for (int ct = 0; ct < NCT; ++ct) {
            bf16x8 bh = *(const bf16x8*)&Bh[(ct * 16 + l16) * BK + lk * 8];
            acc[ct] = __builtin_amdgcn_mfma_f32_16x16x32_bf16(ah, bh, acc[ct], 0, 0, 0);
        }
        if (c + 1 < NCH) {
            __syncthreads();
            storeLDS();
            __syncthreads();
        }
    }

#pragma unroll
    for (int ct = 0; ct < NCT; ++ct) {
        int col = ct * 16 + l16;
#pragma unroll
        for (int r4 = 0; r4 < 4; ++r4) {
            int lr = wv * 16 + lk * 4 + r4;
            int gr = row0 + lr;
            if (gr < n) G[(size_t)gr * COUT + col] = f2bf(acc[ct][r4] * dS[lr]);
        }
    }
}

// ---------- pull-reduce (round-8 structure: sub-wave groups, uint4 gathers) ----------

#define ADD8(u)                                      \
    do {                                             \
        a[0] += bflo((u).x); a[1] += bfhi((u).x);    \
        a[2] += bflo((u).y); a[3] += bfhi((u).y);    \
        a[4] += bflo((u).z); a[5] += bfhi((u).z);    \
        a[6] += bflo((u).w); a[7] += bfhi((u).w);    \
    } while (0)

// Layer 1: 4 groups x 16 lanes; gathers uint4/lane from G1; writes bf16 H + relu.
__global__ __launch_bounds__(256) void k_reduce128(const int* __restrict__ offs,
                                                   const int* __restrict__ srt,
                                                   const uint4* __restrict__ g4,  // [n][16]
                                                   const float* __restrict__ dinv,
                                                   const float* __restrict__ bias,
                                                   unsigned short* __restrict__ out, int n) {
    int node = blockIdx.x * 4 + (threadIdx.x >> 6);
    if (node >= n) return;
    int lane = threadIdx.x & 63;
    int l16 = lane & 15, grp = lane >> 4;
    int beg = offs[node], end = offs[node + 1];

    float a[8] = {};
    if (grp == 0) {  // self-loop term
        uint4 u = g4[(size_t)node * 16 + l16];
        ADD8(u);
    }
    int j = beg + grp;
    for (; j + 12 < end; j += 16) {
        uint4 u0 = g4[(size_t)srt[j]      * 16 + l16];
        uint4 u1 = g4[(size_t)srt[j + 4]  * 16 + l16];
        uint4 u2 = g4[(size_t)srt[j + 8]  * 16 + l16];
        uint4 u3 = g4[(size_t)srt[j + 12] * 16 + l16];
        ADD8(u0); ADD8(u1); ADD8(u2); ADD8(u3);
    }
    for (; j < end; j += 4) {
        uint4 u = g4[(size_t)srt[j] * 16 + l16];
        ADD8(u);
    }
#pragma unroll
    for (int q = 0; q < 8; ++q) {
        a[q] += __shfl_xor(a[q], 16);
        a[q] += __shfl_xor(a[q], 32);
    }
    if (lane < 16) {
        float di = dinv[node];
        ushort8 o;
#pragma unroll
        for (int q = 0; q < 8; ++q) {
            float v = fmaf(di, a[q], bias[l16 * 8 + q]);
            o[q] = f2bf(fmaxf(v, 0.f));  // relu
        }
        *(ushort8*)(out + (size_t)node * 128 + l16 * 8) = o;
    }
}

// Layer 2: 8 groups x 8 lanes; gathers uint4/lane from G2; writes fp32 out (no relu).
__global__ __launch_bounds__(256) void k_reduce64(const int* __restrict__ offs,
                                                  const int* __restrict__ srt,
                                                  const uint4* __restrict__ g4,  // [n][8]
                                                  const float* __restrict__ dinv,
                                                  const float* __restrict__ bias,
                                                  float* __restrict__ out, int n) {
    int node = blockIdx.x * 4 + (threadIdx.x >> 6);
    if (node >= n) return;
    int lane = threadIdx.x & 63;
    int l8 = lane & 7, grp = lane >> 3;
    int beg = offs[node], end = offs[node + 1];

    float a[8] = {};
    if (grp == 0) {  // self-loop term
        uint4 u = g4[(size_t)node * 8 + l8];
        ADD8(u);
    }
    int j = beg + grp;
    for (; j + 8 < end; j += 16) {
        uint4 u0 = g4[(size_t)srt[j]     * 8 + l8];
        uint4 u1 = g4[(size_t)srt[j + 8] * 8 + l8];
        ADD8(u0); ADD8(u1);
    }
    for (; j < end; j += 8) {
        uint4 u = g4[(size_t)srt[j] * 8 + l8];
        ADD8(u);
    }
#pragma unroll
    for (int q = 0; q < 8; ++q) {
        a[q] += __shfl_xor(a[q], 8);
        a[q] += __shfl_xor(a[q], 16);
        a[q] += __shfl_xor(a[q], 32);
    }
    if (lane < 8) {
        float di = dinv[node];
        float4 b0 = ((const float4*)bias)[l8 * 2];
        float4 b1 = ((const float4*)bias)[l8 * 2 + 1];
        float4 o0, o1;
        o0.x = fmaf(di, a[0], b0.x); o0.y = fmaf(di, a[1], b0.y);
        o0.z = fmaf(di, a[2], b0.z); o0.w = fmaf(di, a[3], b0.w);
        o1.x = fmaf(di, a[4], b1.x); o1.y = fmaf(di, a[5], b1.y);
        o1.z = fmaf(di, a[6], b1.z); o1.w = fmaf(di, a[7], b1.w);
        float4* op = (float4*)(out + (size_t)node * 64 + l8 * 8);
        op[0] = o0;
        op[1] = o1;
    }
}

extern "C" void kernel_launch(void* const* d_in, const int* in_sizes, int n_in,
                              void* d_out, int out_size, void* d_ws, size_t ws_size,
                              hipStream_t stream) {
    const float* x  = (const float*)d_in[0];
    const int*   ei = (const int*)d_in[1];   // [2, E] int32
    const float* W1 = (const float*)d_in[2];
    const float* b1 = (const float*)d_in[3];
    const float* W2 = (const float*)d_in[4];
    const float* b2 = (const float*)d_in[5];
    float* out = (float*)d_out;

    const int n = in_sizes[0] / K;   // 50000
    const int e = in_sizes[1] / 2;   // 800000
    const int nb = (n + 255) / 256;  // 196 buckets

    // workspace layout (8B-aligned head first)
    char* p = (char*)d_ws;
    unsigned long long* tmp = (unsigned long long*)p;  p += (size_t)nb * CAP * 8;  // binned pairs
    int* gcur  = (int*)p;  p += 256 * 4;
    int* offs  = (int*)p;  p += (size_t)(n + 1) * 4;
    int* srt   = (int*)p;  p += (size_t)e * 4;
    float* dinv = (float*)p;  p += (size_t)n * 4;
    p = (char*)(((uintptr_t)p + 15) & ~(uintptr_t)15);
    unsigned short* G1 = (unsigned short*)p;  p += (size_t)n * 128 * 2;  // bf16 [n][128]
    p = (char*)(((uintptr_t)p + 15) & ~(uintptr_t)15);
    unsigned short* H = (unsigned short*)p;   p += (size_t)n * 128 * 2;  // bf16 [n][128]
    p = (char*)(((uintptr_t)p + 15) & ~(uintptr_t)15);
    unsigned short* G2 = (unsigned short*)p;                             // bf16 [n][64]

    // CSR build
    hipMemsetAsync(gcur, 0, 256 * sizeof(int), stream);
    k_bin<<<(e + 1023) / 1024, 256, 0, stream>>>(ei, e, gcur, tmp);
    k_csr<<<nb, 1024, 0, stream>>>(tmp, gcur, offs, srt, dinv, n, e);

    // Layer 1: H(bf16) = relu(dinv ⊙ (A_hat G1) + b1), G1 = dinv ⊙ (x@W1)
    k_gemm_mfma<128><<<(n + 63) / 64, 256, 0, stream>>>(x, W1, dinv, G1, n);
    k_reduce128<<<(n + 3) / 4, 256, 0, stream>>>(offs, srt, (const uint4*)G1,
                                                 dinv, b1, H, n);

    // Layer 2: out = dinv ⊙ (A_hat G2) + b2, G2 = dinv ⊙ (H@W2)
    k_gemm_bf16<<<(n + 63) / 64, 256, 0, stream>>>(H, W2, dinv, G2, n);
    k_reduce64<<<(n + 3) / 4, 256, 0, stream>>>(offs, srt, (const uint4*)G2,
                                                dinv, b2, out, n);
}